// Round 13
// baseline (282.610 us; speedup 1.0000x reference)
//
#include <hip/hip_runtime.h>

#define HIDDEN 64
#define N_GRAPHS 64
#define NBMAX 1024            // max coarse buckets (N <= 65536)

typedef unsigned int u32;
typedef unsigned short u16;

typedef __attribute__((ext_vector_type(8))) short short8;
typedef __attribute__((ext_vector_type(4))) float f32x4;

union U4S8 { uint4 u; short8 s; };
union U16x8 { u16 v[8]; uint4 u; };

// ---------------------------------------------------------------------------
static __device__ __forceinline__ float bf_lo(u32 u) { return __uint_as_float(u << 16); }
static __device__ __forceinline__ float bf_hi(u32 u) { return __uint_as_float(u & 0xFFFF0000u); }
static __device__ __forceinline__ u16 f2bf(float f) {          // round-to-nearest-even
    u32 x = __float_as_uint(f);
    return (u16)((x + 0x7FFFu + ((x >> 16) & 1u)) >> 16);
}
static __device__ __forceinline__ u32 pack2(float a, float b) {
    return (u32)f2bf(a) | ((u32)f2bf(b) << 16);
}
static __device__ __forceinline__ float wave_reduce_sum(float v) {
    for (int off = 32; off; off >>= 1) v += __shfl_xor(v, off, 64);
    return v;
}

// ---------------------------------------------------------------------------
// prep: block-partitioned independent prologue jobs (no inter-block deps).
// All h/P/R buffers are TWO PLANES of [N][32] u16 (lo = ch 0-31, hi = 32-63)
// so a gather pass's hot set (one 3.2 MB plane) fits a 4 MB XCD L2.
__global__ __launch_bounds__(256) void prep_kernel(
        const int* __restrict__ dst, u32* __restrict__ hist_g, int E, int NB,
        const float* __restrict__ x,
        const float* __restrict__ W1_rel, const float* __restrict__ W1_root,
        const float* __restrict__ b1,
        u16* __restrict__ Plo, u16* __restrict__ Phi,
        u16* __restrict__ Rlo, u16* __restrict__ Rhi, int N,
        const float* __restrict__ W2_rel, const float* __restrict__ W2_root,
        const float* __restrict__ W3_rel, const float* __restrict__ W3_root,
        u16* __restrict__ Bpk2, u16* __restrict__ Bpk3,
        float* __restrict__ pooled, int* __restrict__ counts,
        int HBLK, int DB) {
    __shared__ u32 lh[NBMAX];
    const int b = blockIdx.x;
    const int tid = threadIdx.x;
    const int lane = tid & 63;

    if (b < HBLK) {                       // ---- histogram ----
        for (int i = tid; i < NB; i += 256) lh[i] = 0;
        __syncthreads();
        const int stride = HBLK * 256;
        for (int e = b * 256 + tid; e < E; e += stride)
            atomicAdd(&lh[dst[e] >> 6], 1u);
        __syncthreads();
        for (int i = tid; i < NB; i += 256)
            if (lh[i]) atomicAdd(&hist_g[i], lh[i]);
    } else if (b < HBLK + DB) {           // ---- dense1 ----
        const int gw = (b - HBLK) * 4 + (tid >> 6);
        const int n0 = gw * 4;
        if (n0 >= N) return;
        const float wr0 = W1_rel[lane], wr1 = W1_rel[64 + lane], wr2 = W1_rel[128 + lane];
        const float wo0 = W1_root[lane], wo1 = W1_root[64 + lane], wo2 = W1_root[128 + lane];
        const float bb = b1[lane];
        u16* Pp = (lane < 32) ? Plo : Phi;
        u16* Rp = (lane < 32) ? Rlo : Rhi;
        const int ch = lane & 31;
        const int n1 = min(n0 + 4, N);
        for (int n = n0; n < n1; ++n) {
            const float x0 = x[n * 3 + 0], x1 = x[n * 3 + 1], x2 = x[n * 3 + 2];
            Pp[(size_t)n * 32 + ch] = f2bf(x0 * wr0 + x1 * wr1 + x2 * wr2);
            Rp[(size_t)n * 32 + ch] = f2bf(x0 * wo0 + x1 * wo1 + x2 * wo2 + bb);
        }
    } else if (b < HBLK + DB + 8) {       // ---- prepack ----
        const int pb = b - HBLK - DB;     // 0..7
        const int layer = pb >> 2;
        const int f = (pb & 3) * 4 + (tid >> 6);
        const int l = lane;
        const float* Wrel  = layer ? W3_rel  : W2_rel;
        const float* Wroot = layer ? W3_root : W2_root;
        u16* Bpk = layer ? Bpk3 : Bpk2;
        const int t = f >> 1, kc = f & 1;
        const int kb = kc * 32 + (l >> 4) * 8;
        const int n = t * 16 + (l & 15);
        U16x8 o;
        #pragma unroll
        for (int j = 0; j < 8; ++j) {
            const int k = kb + j;
            o.v[j] = f2bf((n < 64) ? Wrel[k * 64 + n] : Wroot[k * 64 + (n - 64)]);
        }
        ((uint4*)Bpk)[f * 64 + l] = o.u;
    } else {                              // ---- zero pooled/counts ----
        for (int i = tid; i < N_GRAPHS * HIDDEN; i += 256) pooled[i] = 0.f;
        if (tid < N_GRAPHS) counts[tid] = 0;
    }
}

// ---------------------------------------------------------------------------
// B: exclusive scan of bucket counts -> boff[0..NB], cursor copy, rowptr[N]=E
__global__ __launch_bounds__(1024) void bscan_kernel(
        const u32* __restrict__ hist_g, u32* __restrict__ boff,
        u32* __restrict__ cursor_g, int* __restrict__ rowptr, int NB, int N, int E) {
    __shared__ u32 s[NBMAX];
    const int t = threadIdx.x;
    u32 v = (t < NB) ? hist_g[t] : 0;
    s[t] = v;
    __syncthreads();
    for (int off = 1; off < 1024; off <<= 1) {
        u32 u = (t >= off) ? s[t - off] : 0;
        __syncthreads();
        s[t] += u;
        __syncthreads();
    }
    if (t < NB) {
        u32 ex = s[t] - v;
        boff[t] = ex;
        cursor_g[t] = ex;
    }
    if (t == 0) { boff[NB] = (u32)E; rowptr[N] = E; }
}

// C: partition edges into bucket regions.
__global__ __launch_bounds__(256) void partition_kernel(
        const int* __restrict__ src, const int* __restrict__ dst,
        u32* __restrict__ cursor_g, u32* __restrict__ ebuf, int E, int NB, int K) {
    __shared__ u32 lh[NBMAX];
    __shared__ u32 res[NBMAX];
    const int tid = threadIdx.x;
    const int e0 = blockIdx.x * K;
    const int e1 = min(e0 + K, E);
    for (int i = tid; i < NB; i += 256) lh[i] = 0;
    __syncthreads();
    for (int e = e0 + tid; e < e1; e += 256)
        atomicAdd(&lh[dst[e] >> 6], 1u);
    __syncthreads();
    for (int i = tid; i < NB; i += 256) {
        const u32 c = lh[i];
        if (c) res[i] = atomicAdd(&cursor_g[i], c);
    }
    __syncthreads();
    for (int e = e0 + tid; e < e1; e += 256) {
        const int d = dst[e];
        const u32 p = atomicAdd(&res[d >> 6], 1u);
        ebuf[p] = ((u32)(d & 63) << 16) | (u32)src[e];
    }
}

// D: per-bucket CSR finalize (single XCD owns each output region).
__global__ __launch_bounds__(256) void bucket_kernel(
        const u32* __restrict__ boff, const u32* __restrict__ ebuf,
        int* __restrict__ rowptr, int* __restrict__ csr_src, int N) {
    __shared__ u32 h64[64];
    __shared__ u32 cur[64];
    const int b = blockIdx.x;
    const int tid = threadIdx.x;
    const u32 base = boff[b];
    const u32 end = boff[b + 1];
    if (tid < 64) h64[tid] = 0;
    __syncthreads();
    for (u32 i = base + tid; i < end; i += 256)
        atomicAdd(&h64[ebuf[i] >> 16], 1u);
    __syncthreads();
    if (tid == 0) {
        u32 run = base;
        #pragma unroll
        for (int i = 0; i < 64; ++i) { cur[i] = run; run += h64[i]; }
    }
    __syncthreads();
    if (tid < 64) {
        const int node = b * 64 + tid;
        if (node < N) rowptr[node] = (int)cur[tid];
    }
    __syncthreads();
    for (u32 i = base + tid; i < end; i += 256) {
        const u32 v = ebuf[i];
        const u32 p = atomicAdd(&cur[v >> 16], 1u);
        csr_src[p] = (int)(v & 0xFFFFu);
    }
}

// ---------------------------------------------------------------------------
// dense (64->64): [16 nodes x 64] @ [64 x 128] per wave via 16 MFMAs.
// h planes in, P/R planes out.
__global__ __launch_bounds__(256) void dense_mfma_kernel(
        const u16* __restrict__ hlo, const u16* __restrict__ hhi,
        const u16* __restrict__ Bpk, const float* __restrict__ bias,
        u16* __restrict__ Plo, u16* __restrict__ Phi,
        u16* __restrict__ Rlo, u16* __restrict__ Rhi, int Ngrp) {
    const int lane = threadIdx.x & 63;
    const int wid = (blockIdx.x * 256 + threadIdx.x) >> 6;
    if (wid >= Ngrp) return;

    U4S8 bf[16];
    const uint4* bp = (const uint4*)Bpk;
    #pragma unroll
    for (int f = 0; f < 16; ++f) bf[f].u = bp[f * 64 + lane];

    const int n0 = wid * 16;
    const int row = lane & 15, quad = lane >> 4;
    U4S8 a0, a1;
    a0.u = *(const uint4*)(hlo + (size_t)(n0 + row) * 32 + quad * 8);
    a1.u = *(const uint4*)(hhi + (size_t)(n0 + row) * 32 + quad * 8);

    f32x4 acc[8];
    #pragma unroll
    for (int t = 0; t < 8; ++t) {
        f32x4 z = {0.f, 0.f, 0.f, 0.f};
        z = __builtin_amdgcn_mfma_f32_16x16x32_bf16(a0.s, bf[t * 2 + 0].s, z, 0, 0, 0);
        acc[t] = __builtin_amdgcn_mfma_f32_16x16x32_bf16(a1.s, bf[t * 2 + 1].s, z, 0, 0, 0);
    }

    const int col = lane & 15;
    #pragma unroll
    for (int t = 0; t < 4; ++t) {
        const int ch = t * 16 + col;
        u16* Pp = (t < 2) ? Plo : Phi;
        const int pos = ch & 31;
        #pragma unroll
        for (int r = 0; r < 4; ++r) {
            const int node = n0 + quad * 4 + r;
            Pp[(size_t)node * 32 + pos] = f2bf(acc[t][r]);
        }
    }
    #pragma unroll
    for (int t = 0; t < 4; ++t) {
        const int ch = t * 16 + col;
        u16* Rp = (t < 2) ? Rlo : Rhi;
        const int pos = ch & 31;
        const float bb = bias[ch];
        #pragma unroll
        for (int r = 0; r < 4; ++r) {
            const int node = n0 + quad * 4 + r;
            Rp[(size_t)node * 32 + pos] = f2bf(acc[4 + t][r] + bb);
        }
    }
}

// ---------------------------------------------------------------------------
// gather over ONE 32-channel plane: h_out[i] = act(sum_{j->i} P[j] + R[i]).
// One wave per node; 16 lane-groups x 4 chunks (64B row) -> 16 rows per load
// instruction; deg-adaptive unroll.  Hot set = one 3.2 MB plane (fits L2).
template <bool RELU>
__global__ __launch_bounds__(256) void gather_plane_kernel(
        const u16* __restrict__ P, u16* __restrict__ R_h,
        const int* __restrict__ rowptr, const int* __restrict__ csr_src, int N) {
    const int lane = threadIdx.x & 63;
    const int grp = lane >> 2;       // 16 neighbor slots per round-step
    const int c = lane & 3;          // 4 x 16B chunks (8 bf16 channels each)
    const int node = (blockIdx.x * 256 + threadIdx.x) >> 6;
    if (node >= N) return;
    const int start = rowptr[node];
    const int end = rowptr[node + 1];

    uint4 rv = make_uint4(0u, 0u, 0u, 0u);
    if (lane < 4) rv = *((const uint4*)(R_h + (size_t)node * 32) + lane);

    float acc[8] = {0.f, 0.f, 0.f, 0.f, 0.f, 0.f, 0.f, 0.f};

    for (int base = start; base < end; base += 64) {
        const int m = end - base;    // wave-uniform
        int j[4];
        uint4 v[4];
        #pragma unroll
        for (int u = 0; u < 4; ++u)
            if (u * 16 < m) j[u] = csr_src[min(base + u * 16 + grp, end - 1)];
        #pragma unroll
        for (int u = 0; u < 4; ++u)
            if (u * 16 < m) v[u] = *((const uint4*)(P + (size_t)j[u] * 32) + c);
        #pragma unroll
        for (int u = 0; u < 4; ++u) {
            if (u * 16 < m && base + u * 16 + grp < end) {
                acc[0] += bf_lo(v[u].x); acc[1] += bf_hi(v[u].x);
                acc[2] += bf_lo(v[u].y); acc[3] += bf_hi(v[u].y);
                acc[4] += bf_lo(v[u].z); acc[5] += bf_hi(v[u].z);
                acc[6] += bf_lo(v[u].w); acc[7] += bf_hi(v[u].w);
            }
        }
    }
    #pragma unroll
    for (int off = 4; off <= 32; off <<= 1) {
        #pragma unroll
        for (int i = 0; i < 8; ++i) acc[i] += __shfl_xor(acc[i], off, 64);
    }
    if (lane < 4) {
        float o[8];
        o[0] = acc[0] + bf_lo(rv.x); o[1] = acc[1] + bf_hi(rv.x);
        o[2] = acc[2] + bf_lo(rv.y); o[3] = acc[3] + bf_hi(rv.y);
        o[4] = acc[4] + bf_lo(rv.z); o[5] = acc[5] + bf_hi(rv.z);
        o[6] = acc[6] + bf_lo(rv.w); o[7] = acc[7] + bf_hi(rv.w);
        if (RELU) {
            #pragma unroll
            for (int i = 0; i < 8; ++i) o[i] = fmaxf(o[i], 0.f);
        }
        uint4 sv;
        sv.x = pack2(o[0], o[1]); sv.y = pack2(o[2], o[3]);
        sv.z = pack2(o[4], o[5]); sv.w = pack2(o[6], o[7]);
        *((uint4*)(R_h + (size_t)node * 32) + lane) = sv;
    }
}

// ---------------------------------------------------------------------------
// Global mean pool over plane-pair h: 32 nodes per wave, register
// accumulation, flush on graph transitions (batch sorted, 63 boundaries).
__global__ __launch_bounds__(256) void pool_kernel(
        const u16* __restrict__ hlo, const u16* __restrict__ hhi,
        const int* __restrict__ batch,
        float* __restrict__ pooled, int* __restrict__ counts, int N) {
    const int lane = threadIdx.x & 63;
    const int grp = lane >> 3, c = lane & 7;
    const u16* hbase = (c < 4) ? hlo : hhi;
    const int coff = (c & 3) * 8;
    const int wid = (blockIdx.x * 256 + threadIdx.x) >> 6;
    const int base0 = wid * 32;
    if (base0 >= N) return;
    const int base1 = min(base0 + 32, N);

    float acc[8] = {0.f, 0.f, 0.f, 0.f, 0.f, 0.f, 0.f, 0.f};
    int cnt = 0;
    int g_cur = batch[base0];

    for (int base = base0; base < base1; base += 8) {
        const int n = base + grp;
        const bool valid = (n < base1);
        const int gl = valid ? batch[n] : -1;
        uint4 v = make_uint4(0, 0, 0, 0);
        if (valid) v = *(const uint4*)(hbase + (size_t)n * 32 + coff);
        const bool uni = __all((!valid) || (gl == g_cur));
        if (uni) {
            acc[0] += bf_lo(v.x); acc[1] += bf_hi(v.x);
            acc[2] += bf_lo(v.y); acc[3] += bf_hi(v.y);
            acc[4] += bf_lo(v.z); acc[5] += bf_hi(v.z);
            acc[6] += bf_lo(v.w); acc[7] += bf_hi(v.w);
            cnt += min(8, base1 - base);
        } else {
            float t[8];
            #pragma unroll
            for (int i = 0; i < 8; ++i) t[i] = acc[i];
            #pragma unroll
            for (int off = 8; off <= 32; off <<= 1) {
                #pragma unroll
                for (int i = 0; i < 8; ++i) t[i] += __shfl_xor(t[i], off, 64);
            }
            if (lane < 8) {
                #pragma unroll
                for (int i = 0; i < 8; ++i)
                    atomicAdd(&pooled[g_cur * 64 + lane * 8 + i], t[i]);
            }
            if (lane == 0) atomicAdd(&counts[g_cur], cnt);
            #pragma unroll
            for (int i = 0; i < 8; ++i) acc[i] = 0.f;
            cnt = 0;
            if (valid) {
                atomicAdd(&pooled[gl * 64 + c * 8 + 0], bf_lo(v.x));
                atomicAdd(&pooled[gl * 64 + c * 8 + 1], bf_hi(v.x));
                atomicAdd(&pooled[gl * 64 + c * 8 + 2], bf_lo(v.y));
                atomicAdd(&pooled[gl * 64 + c * 8 + 3], bf_hi(v.y));
                atomicAdd(&pooled[gl * 64 + c * 8 + 4], bf_lo(v.z));
                atomicAdd(&pooled[gl * 64 + c * 8 + 5], bf_hi(v.z));
                atomicAdd(&pooled[gl * 64 + c * 8 + 6], bf_lo(v.w));
                atomicAdd(&pooled[gl * 64 + c * 8 + 7], bf_hi(v.w));
                if (c == 0) atomicAdd(&counts[gl], 1);
            }
            g_cur = __shfl(gl, 56, 64);
        }
    }
    if (cnt > 0 && g_cur >= 0) {
        #pragma unroll
        for (int off = 8; off <= 32; off <<= 1) {
            #pragma unroll
            for (int i = 0; i < 8; ++i) acc[i] += __shfl_xor(acc[i], off, 64);
        }
        if (lane < 8) {
            #pragma unroll
            for (int i = 0; i < 8; ++i)
                atomicAdd(&pooled[g_cur * 64 + lane * 8 + i], acc[i]);
        }
        if (lane == 0) atomicAdd(&counts[g_cur], cnt);
    }
}

__global__ void head_kernel(const float* __restrict__ pooled, const int* __restrict__ counts,
                            const float* __restrict__ lin1_w, const float* __restrict__ lin1_b,
                            const float* __restrict__ lin2_w, const float* __restrict__ lin2_b,
                            float* __restrict__ out) {
    const int g = blockIdx.x;
    const int lane = threadIdx.x;
    const float c = fmaxf((float)counts[g], 1.0f);
    const float p = pooled[g * 64 + lane] / c;
    float d1 = wave_reduce_sum(p * lin1_w[lane]);
    float d2 = wave_reduce_sum(p * lin2_w[lane]);
    if (lane == 0) {
        out[g] = d1 + lin1_b[0];
        out[N_GRAPHS + g] = d2 + lin2_b[0];
    }
}

// ---------------------------------------------------------------------------
extern "C" void kernel_launch(void* const* d_in, const int* in_sizes, int n_in,
                              void* d_out, int out_size, void* d_ws, size_t ws_size,
                              hipStream_t stream) {
    const float* x       = (const float*)d_in[0];
    const int*   ei      = (const int*)d_in[1];
    const int*   batch   = (const int*)d_in[2];
    const float* W1_rel  = (const float*)d_in[3];
    const float* W1_root = (const float*)d_in[4];
    const float* b1      = (const float*)d_in[5];
    const float* W2_rel  = (const float*)d_in[6];
    const float* W2_root = (const float*)d_in[7];
    const float* b2      = (const float*)d_in[8];
    const float* W3_rel  = (const float*)d_in[9];
    const float* W3_root = (const float*)d_in[10];
    const float* b3      = (const float*)d_in[11];
    const float* lin1_w  = (const float*)d_in[12];
    const float* lin1_b  = (const float*)d_in[13];
    const float* lin2_w  = (const float*)d_in[14];
    const float* lin2_b  = (const float*)d_in[15];

    const int N = in_sizes[0] / 3;       // 50000 (< 65536, required for packing)
    const int E = in_sizes[1] / 2;       // 800000
    const int* src = ei;
    const int* dst = ei + E;
    const int NB = (N + 63) / 64;        // 782 coarse buckets

    char* ws = (char*)d_ws;
    size_t off = 0;
    auto alloc = [&](size_t bytes) -> void* {
        void* p = ws + off;
        off += (bytes + 255) & ~(size_t)255;
        return p;
    };
    u32* hist_g   = (u32*)alloc((size_t)NB * 4);
    u32* boff     = (u32*)alloc((size_t)(NB + 1) * 4);
    u32* cursor_g = (u32*)alloc((size_t)NB * 4);
    int* rowptr   = (int*)alloc((size_t)(N + 1) * 4);
    int* csr_src  = (int*)alloc((size_t)E * 4);
    u32* ebuf     = (u32*)alloc((size_t)E * 4);
    const size_t PL = (size_t)N * 32;    // one plane = N x 32 u16
    u16* bufA     = (u16*)alloc(PL * 2 * 2);
    u16* bufP     = (u16*)alloc(PL * 2 * 2);
    u16* bufB     = (u16*)alloc(PL * 2 * 2);
    u16* Bpk2     = (u16*)alloc(16 * 512 * 2);
    u16* Bpk3     = (u16*)alloc(16 * 512 * 2);
    float* pooled = (float*)alloc((size_t)N_GRAPHS * HIDDEN * 4);
    int* counts   = (int*)alloc((size_t)N_GRAPHS * 4);

    u16* bufA_lo = bufA;            u16* bufA_hi = bufA + PL;
    u16* bufP_lo = bufP;            u16* bufP_hi = bufP + PL;
    u16* bufB_lo = bufB;            u16* bufB_hi = bufB + PL;

    (void)hipMemsetAsync(hist_g, 0, (size_t)NB * 4, stream);

    // ---- prologue: hist + dense1 + prepack + zero in ONE kernel ----
    const int HBLK = 128;
    const int DB = (N + 15) / 16;
    prep_kernel<<<HBLK + DB + 9, 256, 0, stream>>>(
        dst, hist_g, E, NB, x, W1_rel, W1_root, b1,
        bufP_lo, bufP_hi, bufB_lo, bufB_hi, N,
        W2_rel, W2_root, W3_rel, W3_root, Bpk2, Bpk3, pooled, counts, HBLK, DB);

    // ---- CSR build (round-9 configuration: 64-node buckets, K=4096) ----
    const int K = 4096;
    const int cb = (E + K - 1) / K;      // 196 blocks
    bscan_kernel<<<1, 1024, 0, stream>>>(hist_g, boff, cursor_g, rowptr, NB, N, E);
    partition_kernel<<<cb, 256, 0, stream>>>(src, dst, cursor_g, ebuf, E, NB, K);
    bucket_kernel<<<NB, 256, 0, stream>>>(boff, ebuf, rowptr, csr_src, N);

    // ---- layers: per-plane gathers (hot set fits XCD L2) + MFMA dense ----
    const int gb = (N + 3) / 4;          // gather: 1 node/wave, 4 waves/block
    const int Ngrp = (N + 15) / 16;
    const int mb = (Ngrp + 3) / 4;

    gather_plane_kernel<true ><<<gb, 256, 0, stream>>>(bufP_lo, bufB_lo, rowptr, csr_src, N);
    gather_plane_kernel<true ><<<gb, 256, 0, stream>>>(bufP_hi, bufB_hi, rowptr, csr_src, N);
    dense_mfma_kernel<<<mb, 256, 0, stream>>>(bufB_lo, bufB_hi, Bpk2, b2,
                                              bufP_lo, bufP_hi, bufA_lo, bufA_hi, Ngrp);
    gather_plane_kernel<true ><<<gb, 256, 0, stream>>>(bufP_lo, bufA_lo, rowptr, csr_src, N);
    gather_plane_kernel<true ><<<gb, 256, 0, stream>>>(bufP_hi, bufA_hi, rowptr, csr_src, N);
    dense_mfma_kernel<<<mb, 256, 0, stream>>>(bufA_lo, bufA_hi, Bpk3, b3,
                                              bufP_lo, bufP_hi, bufB_lo, bufB_hi, Ngrp);
    gather_plane_kernel<false><<<gb, 256, 0, stream>>>(bufP_lo, bufB_lo, rowptr, csr_src, N);
    gather_plane_kernel<false><<<gb, 256, 0, stream>>>(bufP_hi, bufB_hi, rowptr, csr_src, N);

    // ---- pool + heads ----
    const int pool_waves = (N + 31) / 32;
    const int pool_blocks = (pool_waves + 3) / 4;
    pool_kernel<<<pool_blocks, 256, 0, stream>>>(bufB_lo, bufB_hi, batch, pooled, counts, N);
    head_kernel<<<N_GRAPHS, 64, 0, stream>>>(pooled, counts, lin1_w, lin1_b, lin2_w, lin2_b,
                                             (float*)d_out);
}

// Round 14
// 237.852 us; speedup vs baseline: 1.1882x; 1.1882x over previous
//
#include <hip/hip_runtime.h>

#define HIDDEN 64
#define N_GRAPHS 64
#define NBMAX 1024            // max coarse buckets (N <= 65536)

typedef unsigned int u32;
typedef unsigned short u16;

typedef __attribute__((ext_vector_type(8))) short short8;
typedef __attribute__((ext_vector_type(4))) float f32x4;

union U4S8 { uint4 u; short8 s; };
union U16x8 { u16 v[8]; uint4 u; };

// ---------------------------------------------------------------------------
static __device__ __forceinline__ float bf_lo(u32 u) { return __uint_as_float(u << 16); }
static __device__ __forceinline__ float bf_hi(u32 u) { return __uint_as_float(u & 0xFFFF0000u); }
static __device__ __forceinline__ u16 f2bf(float f) {          // round-to-nearest-even
    u32 x = __float_as_uint(f);
    return (u16)((x + 0x7FFFu + ((x >> 16) & 1u)) >> 16);
}
static __device__ __forceinline__ u32 pack2(float a, float b) {
    return (u32)f2bf(a) | ((u32)f2bf(b) << 16);
}
static __device__ __forceinline__ float wave_reduce_sum(float v) {
    for (int off = 32; off; off >>= 1) v += __shfl_xor(v, off, 64);
    return v;
}

// ---------------------------------------------------------------------------
// prep: block-partitioned independent prologue jobs (no inter-block deps):
//   blocks [0, HBLK)            : LDS-privatized coarse histogram of dst>>6
//   blocks [HBLK, HBLK+DB)      : dense1 (P = x@W1_rel, R = x@W1_root + b1)
//   blocks [HBLK+DB, +8)        : prepack W2/W3 into MFMA B-fragment order
//   block  HBLK+DB+8            : zero pooled/counts
__global__ __launch_bounds__(256) void prep_kernel(
        const int* __restrict__ dst, u32* __restrict__ hist_g, int E, int NB,
        const float* __restrict__ x,
        const float* __restrict__ W1_rel, const float* __restrict__ W1_root,
        const float* __restrict__ b1,
        u16* __restrict__ P, u16* __restrict__ R, int N,
        const float* __restrict__ W2_rel, const float* __restrict__ W2_root,
        const float* __restrict__ W3_rel, const float* __restrict__ W3_root,
        u16* __restrict__ Bpk2, u16* __restrict__ Bpk3,
        float* __restrict__ pooled, int* __restrict__ counts,
        int HBLK, int DB) {
    __shared__ u32 lh[NBMAX];
    const int b = blockIdx.x;
    const int tid = threadIdx.x;
    const int lane = tid & 63;

    if (b < HBLK) {                       // ---- histogram ----
        for (int i = tid; i < NB; i += 256) lh[i] = 0;
        __syncthreads();
        const int stride = HBLK * 256;
        for (int e = b * 256 + tid; e < E; e += stride)
            atomicAdd(&lh[dst[e] >> 6], 1u);
        __syncthreads();
        for (int i = tid; i < NB; i += 256)
            if (lh[i]) atomicAdd(&hist_g[i], lh[i]);
    } else if (b < HBLK + DB) {           // ---- dense1 ----
        const int gw = (b - HBLK) * 4 + (tid >> 6);
        const int n0 = gw * 4;
        if (n0 >= N) return;
        const float wr0 = W1_rel[lane], wr1 = W1_rel[64 + lane], wr2 = W1_rel[128 + lane];
        const float wo0 = W1_root[lane], wo1 = W1_root[64 + lane], wo2 = W1_root[128 + lane];
        const float bb = b1[lane];
        const int n1 = min(n0 + 4, N);
        for (int n = n0; n < n1; ++n) {
            const float x0 = x[n * 3 + 0], x1 = x[n * 3 + 1], x2 = x[n * 3 + 2];
            P[(size_t)n * 64 + lane] = f2bf(x0 * wr0 + x1 * wr1 + x2 * wr2);
            R[(size_t)n * 64 + lane] = f2bf(x0 * wo0 + x1 * wo1 + x2 * wo2 + bb);
        }
    } else if (b < HBLK + DB + 8) {       // ---- prepack ----
        const int pb = b - HBLK - DB;     // 0..7
        const int layer = pb >> 2;
        const int f = (pb & 3) * 4 + (tid >> 6);
        const int l = lane;
        const float* Wrel  = layer ? W3_rel  : W2_rel;
        const float* Wroot = layer ? W3_root : W2_root;
        u16* Bpk = layer ? Bpk3 : Bpk2;
        const int t = f >> 1, kc = f & 1;
        const int kb = kc * 32 + (l >> 4) * 8;
        const int n = t * 16 + (l & 15);
        U16x8 o;
        #pragma unroll
        for (int j = 0; j < 8; ++j) {
            const int k = kb + j;
            o.v[j] = f2bf((n < 64) ? Wrel[k * 64 + n] : Wroot[k * 64 + (n - 64)]);
        }
        ((uint4*)Bpk)[f * 64 + l] = o.u;
    } else {                              // ---- zero pooled/counts ----
        for (int i = tid; i < N_GRAPHS * HIDDEN; i += 256) pooled[i] = 0.f;
        if (tid < N_GRAPHS) counts[tid] = 0;
    }
}

// ---------------------------------------------------------------------------
// B: exclusive scan of bucket counts -> boff[0..NB], cursor copy, rowptr[N]=E
__global__ __launch_bounds__(1024) void bscan_kernel(
        const u32* __restrict__ hist_g, u32* __restrict__ boff,
        u32* __restrict__ cursor_g, int* __restrict__ rowptr, int NB, int N, int E) {
    __shared__ u32 s[NBMAX];
    const int t = threadIdx.x;
    u32 v = (t < NB) ? hist_g[t] : 0;
    s[t] = v;
    __syncthreads();
    for (int off = 1; off < 1024; off <<= 1) {
        u32 u = (t >= off) ? s[t - off] : 0;
        __syncthreads();
        s[t] += u;
        __syncthreads();
    }
    if (t < NB) {
        u32 ex = s[t] - v;
        boff[t] = ex;
        cursor_g[t] = ex;
    }
    if (t == 0) { boff[NB] = (u32)E; rowptr[N] = E; }
}

// C: partition edges into bucket regions.
__global__ __launch_bounds__(256) void partition_kernel(
        const int* __restrict__ src, const int* __restrict__ dst,
        u32* __restrict__ cursor_g, u32* __restrict__ ebuf, int E, int NB, int K) {
    __shared__ u32 lh[NBMAX];
    __shared__ u32 res[NBMAX];
    const int tid = threadIdx.x;
    const int e0 = blockIdx.x * K;
    const int e1 = min(e0 + K, E);
    for (int i = tid; i < NB; i += 256) lh[i] = 0;
    __syncthreads();
    for (int e = e0 + tid; e < e1; e += 256)
        atomicAdd(&lh[dst[e] >> 6], 1u);
    __syncthreads();
    for (int i = tid; i < NB; i += 256) {
        const u32 c = lh[i];
        if (c) res[i] = atomicAdd(&cursor_g[i], c);
    }
    __syncthreads();
    for (int e = e0 + tid; e < e1; e += 256) {
        const int d = dst[e];
        const u32 p = atomicAdd(&res[d >> 6], 1u);
        ebuf[p] = ((u32)(d & 63) << 16) | (u32)src[e];
    }
}

// D: per-bucket CSR finalize (single XCD owns each output region).
__global__ __launch_bounds__(256) void bucket_kernel(
        const u32* __restrict__ boff, const u32* __restrict__ ebuf,
        int* __restrict__ rowptr, int* __restrict__ csr_src, int N) {
    __shared__ u32 h64[64];
    __shared__ u32 cur[64];
    const int b = blockIdx.x;
    const int tid = threadIdx.x;
    const u32 base = boff[b];
    const u32 end = boff[b + 1];
    if (tid < 64) h64[tid] = 0;
    __syncthreads();
    for (u32 i = base + tid; i < end; i += 256)
        atomicAdd(&h64[ebuf[i] >> 16], 1u);
    __syncthreads();
    if (tid == 0) {
        u32 run = base;
        #pragma unroll
        for (int i = 0; i < 64; ++i) { cur[i] = run; run += h64[i]; }
    }
    __syncthreads();
    if (tid < 64) {
        const int node = b * 64 + tid;
        if (node < N) rowptr[node] = (int)cur[tid];
    }
    __syncthreads();
    for (u32 i = base + tid; i < end; i += 256) {
        const u32 v = ebuf[i];
        const u32 p = atomicAdd(&cur[v >> 16], 1u);
        csr_src[p] = (int)(v & 0xFFFFu);
    }
}

// ---------------------------------------------------------------------------
// dense (64->64): [16 nodes x 64] @ [64 x 128] per wave via 16 MFMAs.
__global__ __launch_bounds__(256) void dense_mfma_kernel(
        const u16* __restrict__ h_in, const u16* __restrict__ Bpk,
        const float* __restrict__ bias, u16* __restrict__ P, u16* __restrict__ R,
        int Ngrp) {
    const int lane = threadIdx.x & 63;
    const int wid = (blockIdx.x * 256 + threadIdx.x) >> 6;
    if (wid >= Ngrp) return;

    U4S8 bf[16];
    const uint4* bp = (const uint4*)Bpk;
    #pragma unroll
    for (int f = 0; f < 16; ++f) bf[f].u = bp[f * 64 + lane];

    const int n0 = wid * 16;
    const int row = lane & 15, quad = lane >> 4;
    const u16* arow = h_in + (size_t)(n0 + row) * 64 + quad * 8;
    U4S8 a0, a1;
    a0.u = *(const uint4*)(arow);
    a1.u = *(const uint4*)(arow + 32);

    f32x4 acc[8];
    #pragma unroll
    for (int t = 0; t < 8; ++t) {
        f32x4 z = {0.f, 0.f, 0.f, 0.f};
        z = __builtin_amdgcn_mfma_f32_16x16x32_bf16(a0.s, bf[t * 2 + 0].s, z, 0, 0, 0);
        acc[t] = __builtin_amdgcn_mfma_f32_16x16x32_bf16(a1.s, bf[t * 2 + 1].s, z, 0, 0, 0);
    }

    const int col = lane & 15;
    #pragma unroll
    for (int t = 0; t < 4; ++t) {
        #pragma unroll
        for (int r = 0; r < 4; ++r) {
            const int node = n0 + quad * 4 + r;
            P[(size_t)node * 64 + t * 16 + col] = f2bf(acc[t][r]);
        }
    }
    #pragma unroll
    for (int t = 0; t < 4; ++t) {
        const float bb = bias[t * 16 + col];
        #pragma unroll
        for (int r = 0; r < 4; ++r) {
            const int node = n0 + quad * 4 + r;
            R[(size_t)node * 64 + t * 16 + col] = f2bf(acc[4 + t][r] + bb);
        }
    }
}

// ---------------------------------------------------------------------------
// gather: h_out[i] = act( sum_{j->i} P[j] + R[i] ).  One wave per node,
// 8 lane-groups x 16B; deg-adaptive unroll (wave-uniform u*8<m guards).
template <bool RELU>
__global__ __launch_bounds__(256) void gather_kernel(
        const u16* __restrict__ P, u16* __restrict__ R_h,
        const int* __restrict__ rowptr, const int* __restrict__ csr_src, int N) {
    const int lane = threadIdx.x & 63;
    const int grp = lane >> 3;       // neighbor slot within a round
    const int c = lane & 7;          // 16B chunk within row (8 bf16 channels)
    const int node = (blockIdx.x * 256 + threadIdx.x) >> 6;
    if (node >= N) return;
    const int start = rowptr[node];
    const int end = rowptr[node + 1];

    uint4 rv = make_uint4(0u, 0u, 0u, 0u);
    if (lane < 8) rv = *((const uint4*)(R_h + (size_t)node * 64) + lane);

    float acc[8] = {0.f, 0.f, 0.f, 0.f, 0.f, 0.f, 0.f, 0.f};

    for (int base = start; base < end; base += 64) {
        const int m = end - base;    // wave-uniform
        int j[8];
        uint4 v[8];
        #pragma unroll
        for (int u = 0; u < 8; ++u)
            if (u * 8 < m) j[u] = csr_src[min(base + u * 8 + grp, end - 1)];
        #pragma unroll
        for (int u = 0; u < 8; ++u)
            if (u * 8 < m) v[u] = *((const uint4*)(P + (size_t)j[u] * 64) + c);
        #pragma unroll
        for (int u = 0; u < 8; ++u) {
            if (u * 8 < m && base + u * 8 + grp < end) {
                acc[0] += bf_lo(v[u].x); acc[1] += bf_hi(v[u].x);
                acc[2] += bf_lo(v[u].y); acc[3] += bf_hi(v[u].y);
                acc[4] += bf_lo(v[u].z); acc[5] += bf_hi(v[u].z);
                acc[6] += bf_lo(v[u].w); acc[7] += bf_hi(v[u].w);
            }
        }
    }
    #pragma unroll
    for (int off = 8; off <= 32; off <<= 1) {
        #pragma unroll
        for (int i = 0; i < 8; ++i) acc[i] += __shfl_xor(acc[i], off, 64);
    }
    if (lane < 8) {
        float o[8];
        o[0] = acc[0] + bf_lo(rv.x); o[1] = acc[1] + bf_hi(rv.x);
        o[2] = acc[2] + bf_lo(rv.y); o[3] = acc[3] + bf_hi(rv.y);
        o[4] = acc[4] + bf_lo(rv.z); o[5] = acc[5] + bf_hi(rv.z);
        o[6] = acc[6] + bf_lo(rv.w); o[7] = acc[7] + bf_hi(rv.w);
        if (RELU) {
            #pragma unroll
            for (int i = 0; i < 8; ++i) o[i] = fmaxf(o[i], 0.f);
        }
        uint4 sv;
        sv.x = pack2(o[0], o[1]); sv.y = pack2(o[2], o[3]);
        sv.z = pack2(o[4], o[5]); sv.w = pack2(o[6], o[7]);
        *((uint4*)(R_h + (size_t)node * 64) + lane) = sv;
    }
}

// ---------------------------------------------------------------------------
// Global mean pool: 32 nodes per wave, register accumulation, flush on
// graph transitions (batch sorted, 63 boundaries).
__global__ __launch_bounds__(256) void pool_kernel(
        const u16* __restrict__ h, const int* __restrict__ batch,
        float* __restrict__ pooled, int* __restrict__ counts, int N) {
    const int lane = threadIdx.x & 63;
    const int grp = lane >> 3, c = lane & 7;
    const int wid = (blockIdx.x * 256 + threadIdx.x) >> 6;
    const int base0 = wid * 32;
    if (base0 >= N) return;
    const int base1 = min(base0 + 32, N);

    float acc[8] = {0.f, 0.f, 0.f, 0.f, 0.f, 0.f, 0.f, 0.f};
    int cnt = 0;
    int g_cur = batch[base0];

    for (int base = base0; base < base1; base += 8) {
        const int n = base + grp;
        const bool valid = (n < base1);
        const int gl = valid ? batch[n] : -1;
        uint4 v = make_uint4(0, 0, 0, 0);
        if (valid) v = *((const uint4*)(h + (size_t)n * 64) + c);
        const bool uni = __all((!valid) || (gl == g_cur));
        if (uni) {
            acc[0] += bf_lo(v.x); acc[1] += bf_hi(v.x);
            acc[2] += bf_lo(v.y); acc[3] += bf_hi(v.y);
            acc[4] += bf_lo(v.z); acc[5] += bf_hi(v.z);
            acc[6] += bf_lo(v.w); acc[7] += bf_hi(v.w);
            cnt += min(8, base1 - base);
        } else {
            float t[8];
            #pragma unroll
            for (int i = 0; i < 8; ++i) t[i] = acc[i];
            #pragma unroll
            for (int off = 8; off <= 32; off <<= 1) {
                #pragma unroll
                for (int i = 0; i < 8; ++i) t[i] += __shfl_xor(t[i], off, 64);
            }
            if (lane < 8) {
                #pragma unroll
                for (int i = 0; i < 8; ++i)
                    atomicAdd(&pooled[g_cur * 64 + lane * 8 + i], t[i]);
            }
            if (lane == 0) atomicAdd(&counts[g_cur], cnt);
            #pragma unroll
            for (int i = 0; i < 8; ++i) acc[i] = 0.f;
            cnt = 0;
            if (valid) {
                atomicAdd(&pooled[gl * 64 + c * 8 + 0], bf_lo(v.x));
                atomicAdd(&pooled[gl * 64 + c * 8 + 1], bf_hi(v.x));
                atomicAdd(&pooled[gl * 64 + c * 8 + 2], bf_lo(v.y));
                atomicAdd(&pooled[gl * 64 + c * 8 + 3], bf_hi(v.y));
                atomicAdd(&pooled[gl * 64 + c * 8 + 4], bf_lo(v.z));
                atomicAdd(&pooled[gl * 64 + c * 8 + 5], bf_hi(v.z));
                atomicAdd(&pooled[gl * 64 + c * 8 + 6], bf_lo(v.w));
                atomicAdd(&pooled[gl * 64 + c * 8 + 7], bf_hi(v.w));
                if (c == 0) atomicAdd(&counts[gl], 1);
            }
            g_cur = __shfl(gl, 56, 64);
        }
    }
    if (cnt > 0 && g_cur >= 0) {
        #pragma unroll
        for (int off = 8; off <= 32; off <<= 1) {
            #pragma unroll
            for (int i = 0; i < 8; ++i) acc[i] += __shfl_xor(acc[i], off, 64);
        }
        if (lane < 8) {
            #pragma unroll
            for (int i = 0; i < 8; ++i)
                atomicAdd(&pooled[g_cur * 64 + lane * 8 + i], acc[i]);
        }
        if (lane == 0) atomicAdd(&counts[g_cur], cnt);
    }
}

__global__ void head_kernel(const float* __restrict__ pooled, const int* __restrict__ counts,
                            const float* __restrict__ lin1_w, const float* __restrict__ lin1_b,
                            const float* __restrict__ lin2_w, const float* __restrict__ lin2_b,
                            float* __restrict__ out) {
    const int g = blockIdx.x;
    const int lane = threadIdx.x;
    const float c = fmaxf((float)counts[g], 1.0f);
    const float p = pooled[g * 64 + lane] / c;
    float d1 = wave_reduce_sum(p * lin1_w[lane]);
    float d2 = wave_reduce_sum(p * lin2_w[lane]);
    if (lane == 0) {
        out[g] = d1 + lin1_b[0];
        out[N_GRAPHS + g] = d2 + lin2_b[0];
    }
}

// ---------------------------------------------------------------------------
extern "C" void kernel_launch(void* const* d_in, const int* in_sizes, int n_in,
                              void* d_out, int out_size, void* d_ws, size_t ws_size,
                              hipStream_t stream) {
    const float* x       = (const float*)d_in[0];
    const int*   ei      = (const int*)d_in[1];
    const int*   batch   = (const int*)d_in[2];
    const float* W1_rel  = (const float*)d_in[3];
    const float* W1_root = (const float*)d_in[4];
    const float* b1      = (const float*)d_in[5];
    const float* W2_rel  = (const float*)d_in[6];
    const float* W2_root = (const float*)d_in[7];
    const float* b2      = (const float*)d_in[8];
    const float* W3_rel  = (const float*)d_in[9];
    const float* W3_root = (const float*)d_in[10];
    const float* b3      = (const float*)d_in[11];
    const float* lin1_w  = (const float*)d_in[12];
    const float* lin1_b  = (const float*)d_in[13];
    const float* lin2_w  = (const float*)d_in[14];
    const float* lin2_b  = (const float*)d_in[15];

    const int N = in_sizes[0] / 3;       // 50000 (< 65536, required for packing)
    const int E = in_sizes[1] / 2;       // 800000
    const int* src = ei;
    const int* dst = ei + E;
    const int NB = (N + 63) / 64;        // 782 coarse buckets

    char* ws = (char*)d_ws;
    size_t off = 0;
    auto alloc = [&](size_t bytes) -> void* {
        void* p = ws + off;
        off += (bytes + 255) & ~(size_t)255;
        return p;
    };
    u32* hist_g   = (u32*)alloc((size_t)NB * 4);
    u32* boff     = (u32*)alloc((size_t)(NB + 1) * 4);
    u32* cursor_g = (u32*)alloc((size_t)NB * 4);
    int* rowptr   = (int*)alloc((size_t)(N + 1) * 4);
    int* csr_src  = (int*)alloc((size_t)E * 4);
    u32* ebuf     = (u32*)alloc((size_t)E * 4);
    u16* bufA     = (u16*)alloc((size_t)N * HIDDEN * 2);
    u16* bufP     = (u16*)alloc((size_t)N * HIDDEN * 2);
    u16* bufB     = (u16*)alloc((size_t)N * HIDDEN * 2);
    u16* Bpk2     = (u16*)alloc(16 * 512 * 2);
    u16* Bpk3     = (u16*)alloc(16 * 512 * 2);
    float* pooled = (float*)alloc((size_t)N_GRAPHS * HIDDEN * 4);
    int* counts   = (int*)alloc((size_t)N_GRAPHS * 4);

    (void)hipMemsetAsync(hist_g, 0, (size_t)NB * 4, stream);

    // ---- prologue: hist + dense1 + prepack + zero in ONE kernel ----
    const int HBLK = 128;
    const int DB = (N + 15) / 16;
    prep_kernel<<<HBLK + DB + 9, 256, 0, stream>>>(
        dst, hist_g, E, NB, x, W1_rel, W1_root, b1, bufP, bufB, N,
        W2_rel, W2_root, W3_rel, W3_root, Bpk2, Bpk3, pooled, counts, HBLK, DB);

    // ---- CSR build (64-node buckets, K=4096) ----
    const int K = 4096;
    const int cb = (E + K - 1) / K;      // 196 blocks
    bscan_kernel<<<1, 1024, 0, stream>>>(hist_g, boff, cursor_g, rowptr, NB, N, E);
    partition_kernel<<<cb, 256, 0, stream>>>(src, dst, cursor_g, ebuf, E, NB, K);
    bucket_kernel<<<NB, 256, 0, stream>>>(boff, ebuf, rowptr, csr_src, N);

    // ---- layers ----
    const int gb = (N + 3) / 4;          // gather: 1 node/wave, 4/block
    const int Ngrp = (N + 15) / 16;
    const int mb = (Ngrp + 3) / 4;

    gather_kernel<true ><<<gb, 256, 0, stream>>>(bufP, bufB, rowptr, csr_src, N);   // h1 in bufB
    dense_mfma_kernel<<<mb, 256, 0, stream>>>(bufB, Bpk2, b2, bufP, bufA, Ngrp);
    gather_kernel<true ><<<gb, 256, 0, stream>>>(bufP, bufA, rowptr, csr_src, N);   // h2 in bufA
    dense_mfma_kernel<<<mb, 256, 0, stream>>>(bufA, Bpk3, b3, bufP, bufB, Ngrp);
    gather_kernel<false><<<gb, 256, 0, stream>>>(bufP, bufB, rowptr, csr_src, N);   // h3 in bufB

    // ---- pool + heads ----
    const int pool_waves = (N + 31) / 32;
    const int pool_blocks = (pool_waves + 3) / 4;
    pool_kernel<<<pool_blocks, 256, 0, stream>>>(bufB, batch, pooled, counts, N);
    head_kernel<<<N_GRAPHS, 64, 0, stream>>>(pooled, counts, lin1_w, lin1_b, lin2_w, lin2_b,
                                             (float*)d_out);
}